// Round 10
// baseline (163.535 us; speedup 1.0000x reference)
//
#include <hip/hip_runtime.h>
#include <hip/hip_bf16.h>
#include <math.h>

// Problem constants (reference: B,S,H,L = 16,128,512,43)
#define BB 16
#define SS 128
#define HH 512
#define LL 43
#define NEGV -10000.0f
#define M_TOT (BB*SS)   // 2048
#define KP 576          // padded K (512 repr + 43 labels + 21 zero), 18 tiles of 32

#define LOG2E 1.44269504088896f
#define TWO_LOG2E 2.88539008177793f
#define LN2 0.69314718055995f

typedef __bf16 bf16_t;
typedef __attribute__((ext_vector_type(8)))  __bf16 bf16x8;
typedef __attribute__((ext_vector_type(16))) float  f32x16;

__device__ __forceinline__ float fast_exp2(float x) { return __builtin_amdgcn_exp2f(x); }
__device__ __forceinline__ float fast_rcp(float x)  { return __builtin_amdgcn_rcpf(x); }
__device__ __forceinline__ float fast_log2(float x) { return __builtin_amdgcn_logf(x); }
__device__ __forceinline__ float exp_fast(float x)  { return fast_exp2(x * LOG2E); }

// ------------------------------------------------------------------
// Kernel 0: split fp32 -> bf16 hi/lo workspace buffers. (unchanged)
// ------------------------------------------------------------------
__global__ __launch_bounds__(256)
void split_kernel(const float* __restrict__ repr, const float* __restrict__ labels,
                  const float* __restrict__ u_w, const float* __restrict__ w_w,
                  bf16_t* __restrict__ Ah, bf16_t* __restrict__ Al,
                  bf16_t* __restrict__ Buh, bf16_t* __restrict__ Bul,
                  bf16_t* __restrict__ Bwh, bf16_t* __restrict__ Bwl) {
    const int tid = threadIdx.x;
    if (blockIdx.x < 288) {
        // ---- weight transpose tiles ----
        const int kt = blockIdx.x >> 4;        // 0..17
        const int nt = blockIdx.x & 15;        // 0..15
        const int k0 = kt * 32, n0 = nt * 32;
        __shared__ float tu[32][33], tw[32][33];
        {
            const int r  = tid >> 3;           // 0..31 (k-row in tile)
            const int c4 = (tid & 7) << 2;     // 0..28 (n-col chunk)
            const int k  = k0 + r;
            float4 fu = make_float4(0.f, 0.f, 0.f, 0.f);
            float4 fw = make_float4(0.f, 0.f, 0.f, 0.f);
            if (k < HH)      fu = *(const float4*)&u_w[(size_t)k * HH + n0 + c4];
            if (k < HH + LL) fw = *(const float4*)&w_w[(size_t)k * HH + n0 + c4];
            tu[r][c4+0] = fu.x; tu[r][c4+1] = fu.y; tu[r][c4+2] = fu.z; tu[r][c4+3] = fu.w;
            tw[r][c4+0] = fw.x; tw[r][c4+1] = fw.y; tw[r][c4+2] = fw.z; tw[r][c4+3] = fw.w;
        }
        __syncthreads();
        {
            const int nr = tid >> 3;           // 0..31 (n-row of Bt)
            const int k4 = (tid & 7) << 2;     // 0..28 (k chunk)
            union { bf16_t h[4]; uint2 v; } uh, ul, wh, wl;
#pragma unroll
            for (int q = 0; q < 4; ++q) {
                float xu = tu[k4 + q][nr];
                float xw = tw[k4 + q][nr];
                bf16_t hu = (bf16_t)xu; bf16_t lu = (bf16_t)(xu - (float)hu);
                bf16_t hw = (bf16_t)xw; bf16_t lw = (bf16_t)(xw - (float)hw);
                uh.h[q] = hu; ul.h[q] = lu; wh.h[q] = hw; wl.h[q] = lw;
            }
            const size_t o = (size_t)(n0 + nr) * KP + k0 + k4;
            *(uint2*)&Buh[o] = uh.v;  *(uint2*)&Bul[o] = ul.v;
            *(uint2*)&Bwh[o] = wh.v;  *(uint2*)&Bwl[o] = wl.v;
        }
    } else {
        // ---- A split: chunk = 4 consecutive k of one m-row ----
        const int chunk = (blockIdx.x - 288) * 256 + tid;   // 0..294911
        const int m  = chunk / 144;                         // KP/4 = 144 chunks per row
        const int c4 = chunk - m * 144;
        const int k  = c4 << 2;
        float x[4];
        if (k <= HH - 4) {
            float4 f = *(const float4*)&repr[(size_t)m * HH + k];
            x[0] = f.x; x[1] = f.y; x[2] = f.z; x[3] = f.w;
        } else {            // k >= 512 here (chunks are 4-aligned, 512 % 4 == 0)
#pragma unroll
            for (int q = 0; q < 4; ++q) {
                const int kk = k + q;
                x[q] = (kk < HH + LL) ? labels[(size_t)m * LL + (kk - HH)] : 0.f;
            }
        }
        union { bf16_t h[4]; uint2 v; } ph, pl;
#pragma unroll
        for (int q = 0; q < 4; ++q) {
            bf16_t hi = (bf16_t)x[q];
            ph.h[q] = hi;
            pl.h[q] = (bf16_t)(x[q] - (float)hi);
        }
        const size_t o = (size_t)m * KP + k;
        *(uint2*)&Ah[o] = ph.v;
        *(uint2*)&Al[o] = pl.v;
    }
}

// ------------------------------------------------------------------
// Kernel 1 (v4): MFMA GEMM, bf16 hi/lo 3-pass. (unchanged)
// ------------------------------------------------------------------
__global__ __launch_bounds__(256)
void gemm_mfma(const bf16_t* __restrict__ Ah, const bf16_t* __restrict__ Al,
               const bf16_t* __restrict__ Buh, const bf16_t* __restrict__ Bul,
               const bf16_t* __restrict__ Bwh, const bf16_t* __restrict__ Bwl,
               const float* __restrict__ u_b, const float* __restrict__ w_b,
               float* __restrict__ u_out, float* __restrict__ w_out) {
    __shared__ bf16_t sm[6][64][40];    // Ah,Al,Buh,Bul,Bwh,Bwl tiles

    const int tid  = threadIdx.x;
    const int bm   = blockIdx.x & 31;
    const int bn   = blockIdx.x >> 5;
    const int m0   = bm * 64, n0 = bn * 64;
    const int wv   = tid >> 6, lane = tid & 63;
    const int wm   = wv >> 1, wn = wv & 1;
    const int ln31 = lane & 31, g = lane >> 5;

    const int sr = tid >> 2;            // stage row 0..63
    const int sc = tid & 3;             // stage 16B chunk 0..3

    f32x16 accu = {0,0,0,0,0,0,0,0,0,0,0,0,0,0,0,0};
    f32x16 accw = {0,0,0,0,0,0,0,0,0,0,0,0,0,0,0,0};

    const size_t aoff = (size_t)(m0 + sr) * KP;
    const size_t boff = (size_t)(n0 + sr) * KP;

    for (int kt = 0; kt < KP / 32; ++kt) {
        const int kc = kt * 32 + sc * 8;          // global k elem of this chunk
        *(uint4*)&sm[0][sr][sc * 8] = *(const uint4*)&Ah [aoff + kc];
        *(uint4*)&sm[1][sr][sc * 8] = *(const uint4*)&Al [aoff + kc];
        *(uint4*)&sm[2][sr][sc * 8] = *(const uint4*)&Buh[boff + kc];
        *(uint4*)&sm[3][sr][sc * 8] = *(const uint4*)&Bul[boff + kc];
        *(uint4*)&sm[4][sr][sc * 8] = *(const uint4*)&Bwh[boff + kc];
        *(uint4*)&sm[5][sr][sc * 8] = *(const uint4*)&Bwl[boff + kc];
        __syncthreads();

#pragma unroll
        for (int ks = 0; ks < 2; ++ks) {
            const int co = ks * 16 + g * 8;       // k-frag col in LDS tile
            bf16x8 a_h = *(const bf16x8*)&sm[0][wm * 32 + ln31][co];
            bf16x8 a_l = *(const bf16x8*)&sm[1][wm * 32 + ln31][co];
            bf16x8 buh = *(const bf16x8*)&sm[2][wn * 32 + ln31][co];
            bf16x8 bul = *(const bf16x8*)&sm[3][wn * 32 + ln31][co];
            bf16x8 bwh = *(const bf16x8*)&sm[4][wn * 32 + ln31][co];
            bf16x8 bwl = *(const bf16x8*)&sm[5][wn * 32 + ln31][co];
            accu = __builtin_amdgcn_mfma_f32_32x32x16_bf16(a_h, buh, accu, 0, 0, 0);
            accu = __builtin_amdgcn_mfma_f32_32x32x16_bf16(a_h, bul, accu, 0, 0, 0);
            accu = __builtin_amdgcn_mfma_f32_32x32x16_bf16(a_l, buh, accu, 0, 0, 0);
            accw = __builtin_amdgcn_mfma_f32_32x32x16_bf16(a_h, bwh, accw, 0, 0, 0);
            accw = __builtin_amdgcn_mfma_f32_32x32x16_bf16(a_h, bwl, accw, 0, 0, 0);
            accw = __builtin_amdgcn_mfma_f32_32x32x16_bf16(a_l, bwh, accw, 0, 0, 0);
        }
        __syncthreads();
    }

    // ---- epilogue: bias + prescale, direct global stores ----
    const int C = n0 + wn * 32 + ln31;
    const float ub = u_b[C], wb = w_b[C];
#pragma unroll
    for (int rg = 0; rg < 16; ++rg) {
        const int m = (rg & 3) + 8 * (rg >> 2) + 4 * g;
        const int R = m0 + wm * 32 + m;
        u_out[(size_t)R * HH + C] = (accu[rg] + ub) * TWO_LOG2E;
        w_out[(size_t)R * HH + C] = (accw[rg] + wb) * TWO_LOG2E;
    }
}

// ------------------------------------------------------------------
// Kernel 2 (v3): j-as-lane scores, ITILE=2, LDS-staged w/v, Vsum trick.
// 1024 blocks = (16 b) x (64 i-pairs), XCD-swizzled.  4 waves:
// wave = (ir in {0,1}) x (jh in {0,1}); lane owns j = jh*64+lane,
// single accumulator; score = Vsum - 2 * sum_h v_h * rcp(exp2(u'+w')+1).
// ------------------------------------------------------------------
__global__ __launch_bounds__(256)
void scores_v3(const float* __restrict__ u, const float* __restrict__ w,
               const float* __restrict__ v_w, const int* __restrict__ heads,
               const int* __restrict__ words,
               float* __restrict__ out,      // [0]=loss (kernel 3), [1..] probs
               float* __restrict__ ce_out) {
    // XCD swizzle: xcd = blk%8 owns b in {2*xcd, 2*xcd+1}
    const int blk = blockIdx.x;               // 0..1023
    const int b   = (blk & 7) * 2 + ((blk >> 3) & 1);
    const int i0  = (blk >> 4) * 2;           // i-pair base

    const int tid  = threadIdx.x;
    const int wv   = tid >> 6;                // 0..3
    const int lane = tid & 63;
    const int ir   = wv >> 1;                 // i-row select
    const int jh   = wv & 1;                  // j-half select
    const int i    = i0 + ir;
    const int j    = jh * 64 + lane;

    __shared__ float sw[2][HH];               // prescaled w rows
    __shared__ float sv[HH];
    __shared__ float s_sc[2][SS];
    __shared__ float s_vsum;

    // cooperative stage: 2*512 + 512 floats as float4 (384 chunks)
    for (int c = tid; c < 384; c += 256) {
        const int seg = c >> 7;               // 0,1 -> w rows; 2 -> v
        const int off = (c & 127) << 2;
        const float* src = (seg == 0) ? &w[(size_t)(b * SS + i0) * HH + off]
                         : (seg == 1) ? &w[(size_t)(b * SS + i0 + 1) * HH + off]
                                      : &v_w[off];
        float* dst = (seg == 0) ? &sw[0][off] : (seg == 1) ? &sw[1][off] : &sv[off];
        *(float4*)dst = *(const float4*)src;
    }
    __syncthreads();

    // Vsum (wave 0 computes; consumed after the next barrier)
    if (wv == 0) {
        float vs = 0.f;
#pragma unroll
        for (int q = 0; q < 8; ++q) vs += sv[lane * 8 + q];
#pragma unroll
        for (int off = 32; off > 0; off >>= 1) vs += __shfl_xor(vs, off);
        if (lane == 0) s_vsum = vs;
    }

    const float* __restrict__ up = &u[(size_t)(b * SS + j) * HH];
    float acc = 0.f;
#pragma unroll 2
    for (int h = 0; h < HH; h += 8) {
        float4 ua = *(const float4*)&up[h];
        float4 ub = *(const float4*)&up[h + 4];
        float4 va = *(const float4*)&sv[h];
        float4 vb = *(const float4*)&sv[h + 4];
        float4 wa = *(const float4*)&sw[ir][h];
        float4 wb = *(const float4*)&sw[ir][h + 4];
#define STEP(UU, VV, WW)                                          \
        acc = fmaf(VV, fast_rcp(fast_exp2(UU + WW) + 1.0f), acc);
        STEP(ua.x, va.x, wa.x)
        STEP(ua.y, va.y, wa.y)
        STEP(ua.z, va.z, wa.z)
        STEP(ua.w, va.w, wa.w)
        STEP(ub.x, vb.x, wb.x)
        STEP(ub.y, vb.y, wb.y)
        STEP(ub.z, vb.z, wb.z)
        STEP(ub.w, vb.w, wb.w)
#undef STEP
    }
    __syncthreads();                           // s_vsum ready; also orders s_sc below

    const float vsum = s_vsum;
    float s = fmaf(-2.0f, acc, vsum);          // = sum_h v*tanh
    const bool colpad = (words[b * SS + j] == 0);
    if (colpad || j == i) s = NEGV;

    s_sc[ir][j] = s;
    if (i >= 1)
        out[1 + (size_t)(b * (SS - 1) + (i - 1)) * SS + j] = exp_fast(s);
    __syncthreads();

    // softmax + CE: jh==0 wave handles its row
    if (jh == 0) {
        float t0 = s_sc[ir][lane];
        float t1 = s_sc[ir][lane + 64];
        float m = fmaxf(t0, t1);
#pragma unroll
        for (int off = 32; off > 0; off >>= 1) m = fmaxf(m, __shfl_xor(m, off));
        float e = exp_fast(t0 - m) + exp_fast(t1 - m);
#pragma unroll
        for (int off = 32; off > 0; off >>= 1) e += __shfl_xor(e, off);

        const int hd = heads[b * SS + i];
        const float sh = s_sc[ir][hd];
        const float ce = m + fast_log2(e) * LN2 - sh;
        if (lane == 0) ce_out[b * SS + i] = (i >= 1) ? ce : 0.f;
    }
}

// ------------------------------------------------------------------
// Kernel 3: deterministic loss reduction (f64 accumulate)
// ------------------------------------------------------------------
__global__ __launch_bounds__(256)
void loss_sum(const float* __restrict__ ce, float* __restrict__ out) {
    __shared__ double sd[256];
    const int tid = threadIdx.x;
    double s = 0.0;
    for (int k = tid; k < M_TOT; k += 256) s += (double)ce[k];
    sd[tid] = s;
    __syncthreads();
    for (int off = 128; off > 0; off >>= 1) {
        if (tid < off) sd[tid] += sd[tid + off];
        __syncthreads();
    }
    if (tid == 0) out[0] = (float)(sd[0] * (1.0 / (double)BB));
}

// ------------------------------------------------------------------
extern "C" void kernel_launch(void* const* d_in, const int* in_sizes, int n_in,
                              void* d_out, int out_size, void* d_ws, size_t ws_size,
                              hipStream_t stream) {
    const float* repr   = (const float*)d_in[0];   // [16,128,512]
    const float* labels = (const float*)d_in[1];   // [16,128,43]
    const int*   heads  = (const int*)d_in[2];     // [16,128]
    const int*   words  = (const int*)d_in[3];     // [16,128]
    // d_in[4] = sent_id (unused)
    const float* u_w    = (const float*)d_in[5];   // [555,512]
    const float* u_b    = (const float*)d_in[6];   // [512]
    const float* w_w    = (const float*)d_in[7];   // [555,512]
    const float* w_b    = (const float*)d_in[8];   // [512]
    const float* v_w    = (const float*)d_in[9];   // [512,1]

    float* out = (float*)d_out;                    // [0]=loss, rest probs [16,127,128]

    // ---- workspace layout (bytes) ----
    char* ws = (char*)d_ws;
    size_t cur = 0;
    float*  u_ws = (float*)(ws + cur);  cur += (size_t)M_TOT * HH * 4;        // 4 MB
    float*  w_ws = (float*)(ws + cur);  cur += (size_t)M_TOT * HH * 4;        // 4 MB
    bf16_t* Ah   = (bf16_t*)(ws + cur); cur += (size_t)M_TOT * KP * 2;        // 2.25 MB
    bf16_t* Al   = (bf16_t*)(ws + cur); cur += (size_t)M_TOT * KP * 2;
    bf16_t* Buh  = (bf16_t*)(ws + cur); cur += (size_t)HH * KP * 2;           // 0.56 MB
    bf16_t* Bul  = (bf16_t*)(ws + cur); cur += (size_t)HH * KP * 2;
    bf16_t* Bwh  = (bf16_t*)(ws + cur); cur += (size_t)HH * KP * 2;
    bf16_t* Bwl  = (bf16_t*)(ws + cur); cur += (size_t)HH * KP * 2;
    float*  ce_ws = (float*)(ws + cur);                                       // 8 KB

    split_kernel<<<dim3(1440), dim3(256), 0, stream>>>(
        repr, labels, u_w, w_w, Ah, Al, Buh, Bul, Bwh, Bwl);
    gemm_mfma<<<dim3(256), dim3(256), 0, stream>>>(
        Ah, Al, Buh, Bul, Bwh, Bwl, u_b, w_b, u_ws, w_ws);
    scores_v3<<<dim3(1024), dim3(256), 0, stream>>>(
        u_ws, w_ws, v_w, heads, words, out, ce_ws);
    loss_sum<<<dim3(1), dim3(256), 0, stream>>>(ce_ws, out);
}

// Round 12
// 155.620 us; speedup vs baseline: 1.0509x; 1.0509x over previous
//
#include <hip/hip_runtime.h>
#include <hip/hip_bf16.h>
#include <math.h>

// Problem constants (reference: B,S,H,L = 16,128,512,43)
#define BB 16
#define SS 128
#define HH 512
#define LL 43
#define NEGV -10000.0f
#define M_TOT (BB*SS)   // 2048
#define KP 576          // padded K (512 repr + 43 labels + 21 zero), 18 tiles of 32

#define LOG2E 1.44269504088896f
#define TWO_LOG2E 2.88539008177793f
#define LN2 0.69314718055995f

typedef __bf16 bf16_t;
typedef __attribute__((ext_vector_type(8)))  __bf16 bf16x8;
typedef __attribute__((ext_vector_type(16))) float  f32x16;

__device__ __forceinline__ float fast_exp2(float x) { return __builtin_amdgcn_exp2f(x); }
__device__ __forceinline__ float fast_rcp(float x)  { return __builtin_amdgcn_rcpf(x); }
__device__ __forceinline__ float fast_log2(float x) { return __builtin_amdgcn_logf(x); }
__device__ __forceinline__ float exp_fast(float x)  { return fast_exp2(x * LOG2E); }

// ------------------------------------------------------------------
// Kernel 0: split fp32 -> bf16 hi/lo workspace buffers. (unchanged)
// ------------------------------------------------------------------
__global__ __launch_bounds__(256)
void split_kernel(const float* __restrict__ repr, const float* __restrict__ labels,
                  const float* __restrict__ u_w, const float* __restrict__ w_w,
                  bf16_t* __restrict__ Ah, bf16_t* __restrict__ Al,
                  bf16_t* __restrict__ Buh, bf16_t* __restrict__ Bul,
                  bf16_t* __restrict__ Bwh, bf16_t* __restrict__ Bwl) {
    const int tid = threadIdx.x;
    if (blockIdx.x < 288) {
        // ---- weight transpose tiles ----
        const int kt = blockIdx.x >> 4;        // 0..17
        const int nt = blockIdx.x & 15;        // 0..15
        const int k0 = kt * 32, n0 = nt * 32;
        __shared__ float tu[32][33], tw[32][33];
        {
            const int r  = tid >> 3;           // 0..31 (k-row in tile)
            const int c4 = (tid & 7) << 2;     // 0..28 (n-col chunk)
            const int k  = k0 + r;
            float4 fu = make_float4(0.f, 0.f, 0.f, 0.f);
            float4 fw = make_float4(0.f, 0.f, 0.f, 0.f);
            if (k < HH)      fu = *(const float4*)&u_w[(size_t)k * HH + n0 + c4];
            if (k < HH + LL) fw = *(const float4*)&w_w[(size_t)k * HH + n0 + c4];
            tu[r][c4+0] = fu.x; tu[r][c4+1] = fu.y; tu[r][c4+2] = fu.z; tu[r][c4+3] = fu.w;
            tw[r][c4+0] = fw.x; tw[r][c4+1] = fw.y; tw[r][c4+2] = fw.z; tw[r][c4+3] = fw.w;
        }
        __syncthreads();
        {
            const int nr = tid >> 3;           // 0..31 (n-row of Bt)
            const int k4 = (tid & 7) << 2;     // 0..28 (k chunk)
            union { bf16_t h[4]; uint2 v; } uh, ul, wh, wl;
#pragma unroll
            for (int q = 0; q < 4; ++q) {
                float xu = tu[k4 + q][nr];
                float xw = tw[k4 + q][nr];
                bf16_t hu = (bf16_t)xu; bf16_t lu = (bf16_t)(xu - (float)hu);
                bf16_t hw = (bf16_t)xw; bf16_t lw = (bf16_t)(xw - (float)hw);
                uh.h[q] = hu; ul.h[q] = lu; wh.h[q] = hw; wl.h[q] = lw;
            }
            const size_t o = (size_t)(n0 + nr) * KP + k0 + k4;
            *(uint2*)&Buh[o] = uh.v;  *(uint2*)&Bul[o] = ul.v;
            *(uint2*)&Bwh[o] = wh.v;  *(uint2*)&Bwl[o] = wl.v;
        }
    } else {
        // ---- A split: chunk = 4 consecutive k of one m-row ----
        const int chunk = (blockIdx.x - 288) * 256 + tid;   // 0..294911
        const int m  = chunk / 144;                         // KP/4 = 144 chunks per row
        const int c4 = chunk - m * 144;
        const int k  = c4 << 2;
        float x[4];
        if (k <= HH - 4) {
            float4 f = *(const float4*)&repr[(size_t)m * HH + k];
            x[0] = f.x; x[1] = f.y; x[2] = f.z; x[3] = f.w;
        } else {            // k >= 512 here (chunks are 4-aligned, 512 % 4 == 0)
#pragma unroll
            for (int q = 0; q < 4; ++q) {
                const int kk = k + q;
                x[q] = (kk < HH + LL) ? labels[(size_t)m * LL + (kk - HH)] : 0.f;
            }
        }
        union { bf16_t h[4]; uint2 v; } ph, pl;
#pragma unroll
        for (int q = 0; q < 4; ++q) {
            bf16_t hi = (bf16_t)x[q];
            ph.h[q] = hi;
            pl.h[q] = (bf16_t)(x[q] - (float)hi);
        }
        const size_t o = (size_t)m * KP + k;
        *(uint2*)&Ah[o] = ph.v;
        *(uint2*)&Al[o] = pl.v;
    }
}

// ------------------------------------------------------------------
// Kernel 1 (v4): MFMA GEMM, bf16 hi/lo 3-pass. (unchanged)
// ------------------------------------------------------------------
__global__ __launch_bounds__(256)
void gemm_mfma(const bf16_t* __restrict__ Ah, const bf16_t* __restrict__ Al,
               const bf16_t* __restrict__ Buh, const bf16_t* __restrict__ Bul,
               const bf16_t* __restrict__ Bwh, const bf16_t* __restrict__ Bwl,
               const float* __restrict__ u_b, const float* __restrict__ w_b,
               float* __restrict__ u_out, float* __restrict__ w_out) {
    __shared__ bf16_t sm[6][64][40];    // Ah,Al,Buh,Bul,Bwh,Bwl tiles

    const int tid  = threadIdx.x;
    const int bm   = blockIdx.x & 31;
    const int bn   = blockIdx.x >> 5;
    const int m0   = bm * 64, n0 = bn * 64;
    const int wv   = tid >> 6, lane = tid & 63;
    const int wm   = wv >> 1, wn = wv & 1;
    const int ln31 = lane & 31, g = lane >> 5;

    const int sr = tid >> 2;            // stage row 0..63
    const int sc = tid & 3;             // stage 16B chunk 0..3

    f32x16 accu = {0,0,0,0,0,0,0,0,0,0,0,0,0,0,0,0};
    f32x16 accw = {0,0,0,0,0,0,0,0,0,0,0,0,0,0,0,0};

    const size_t aoff = (size_t)(m0 + sr) * KP;
    const size_t boff = (size_t)(n0 + sr) * KP;

    for (int kt = 0; kt < KP / 32; ++kt) {
        const int kc = kt * 32 + sc * 8;          // global k elem of this chunk
        *(uint4*)&sm[0][sr][sc * 8] = *(const uint4*)&Ah [aoff + kc];
        *(uint4*)&sm[1][sr][sc * 8] = *(const uint4*)&Al [aoff + kc];
        *(uint4*)&sm[2][sr][sc * 8] = *(const uint4*)&Buh[boff + kc];
        *(uint4*)&sm[3][sr][sc * 8] = *(const uint4*)&Bul[boff + kc];
        *(uint4*)&sm[4][sr][sc * 8] = *(const uint4*)&Bwh[boff + kc];
        *(uint4*)&sm[5][sr][sc * 8] = *(const uint4*)&Bwl[boff + kc];
        __syncthreads();

#pragma unroll
        for (int ks = 0; ks < 2; ++ks) {
            const int co = ks * 16 + g * 8;       // k-frag col in LDS tile
            bf16x8 a_h = *(const bf16x8*)&sm[0][wm * 32 + ln31][co];
            bf16x8 a_l = *(const bf16x8*)&sm[1][wm * 32 + ln31][co];
            bf16x8 buh = *(const bf16x8*)&sm[2][wn * 32 + ln31][co];
            bf16x8 bul = *(const bf16x8*)&sm[3][wn * 32 + ln31][co];
            bf16x8 bwh = *(const bf16x8*)&sm[4][wn * 32 + ln31][co];
            bf16x8 bwl = *(const bf16x8*)&sm[5][wn * 32 + ln31][co];
            accu = __builtin_amdgcn_mfma_f32_32x32x16_bf16(a_h, buh, accu, 0, 0, 0);
            accu = __builtin_amdgcn_mfma_f32_32x32x16_bf16(a_h, bul, accu, 0, 0, 0);
            accu = __builtin_amdgcn_mfma_f32_32x32x16_bf16(a_l, buh, accu, 0, 0, 0);
            accw = __builtin_amdgcn_mfma_f32_32x32x16_bf16(a_h, bwh, accw, 0, 0, 0);
            accw = __builtin_amdgcn_mfma_f32_32x32x16_bf16(a_h, bwl, accw, 0, 0, 0);
            accw = __builtin_amdgcn_mfma_f32_32x32x16_bf16(a_l, bwh, accw, 0, 0, 0);
        }
        __syncthreads();
    }

    // ---- epilogue: bias + prescale, direct global stores ----
    const int C = n0 + wn * 32 + ln31;
    const float ub = u_b[C], wb = w_b[C];
#pragma unroll
    for (int rg = 0; rg < 16; ++rg) {
        const int m = (rg & 3) + 8 * (rg >> 2) + 4 * g;
        const int R = m0 + wm * 32 + m;
        u_out[(size_t)R * HH + C] = (accu[rg] + ub) * TWO_LOG2E;
        w_out[(size_t)R * HH + C] = (accw[rg] + wb) * TWO_LOG2E;
    }
}

// ------------------------------------------------------------------
// Kernel 2 (v5): split-H scores.  Block = (b, 2 i-rows), 4 waves =
// (hh h-half) x (jh j-half).  Each wave: 2 rows x 64 j x 256 h with
// w/v as WAVE-UNIFORM GLOBAL loads (scalar pipe, zero LDS in hot loop
// — v2's proven pattern) and per-lane u loads.  Partials combined via
// 2KB LDS once.  4096 waves = 16/CU = 4/SIMD (2x v2's TLP).
// score = Vsum - 2 * sum_h v_h * rcp(exp2(u'+w')+1).
// ------------------------------------------------------------------
__global__ __launch_bounds__(256)
void scores_v5(const float* __restrict__ u, const float* __restrict__ w,
               const float* __restrict__ v_w, const int* __restrict__ heads,
               const int* __restrict__ words,
               float* __restrict__ out,      // [0]=loss (kernel 3), [1..] probs
               float* __restrict__ ce_out) {
    // XCD swizzle: xcd = blk%8 owns b in {2*xcd, 2*xcd+1}
    const int blk = blockIdx.x;               // 0..1023
    const int b   = (blk & 7) * 2 + ((blk >> 3) & 1);
    const int i0  = (blk >> 4) * 2;           // i-pair base

    const int tid  = threadIdx.x;
    const int wv   = tid >> 6;                // 0..3
    const int lane = tid & 63;
    const int hh   = wv >> 1;                 // h-half select
    const int jh   = wv & 1;                  // j-half select
    const int j    = jh * 64 + lane;
    const int h0   = hh * (HH / 2);

    __shared__ float part[2][2][SS];          // [hh][row][j]
    __shared__ float s_sc[2][SS];
    __shared__ float s_vsum;

    // Vsum (wave 0; consumed by hh==0 waves after the first barrier)
    if (wv == 0) {
        float4 a = *(const float4*)&v_w[lane * 8];
        float4 c = *(const float4*)&v_w[lane * 8 + 4];
        float vs = a.x + a.y + a.z + a.w + c.x + c.y + c.z + c.w;
#pragma unroll
        for (int off = 32; off > 0; off >>= 1) vs += __shfl_xor(vs, off);
        if (lane == 0) s_vsum = vs;
    }

    const float* __restrict__ up  = &u[(size_t)(b * SS + j) * HH + h0];
    const float* __restrict__ w0p = &w[(size_t)(b * SS + i0) * HH + h0];  // uniform
    const float* __restrict__ w1p = w0p + HH;                             // uniform
    const float* __restrict__ vp  = &v_w[h0];                             // uniform

    float acc0 = 0.f, acc1 = 0.f;
#pragma unroll 2
    for (int h = 0; h < HH / 2; h += 8) {
        float4 ua  = *(const float4*)&up[h];
        float4 ub  = *(const float4*)&up[h + 4];
        float4 va  = *(const float4*)&vp[h];       // uniform -> s_load
        float4 vb  = *(const float4*)&vp[h + 4];
        float4 w0a = *(const float4*)&w0p[h];      // uniform -> s_load
        float4 w0b = *(const float4*)&w0p[h + 4];
        float4 w1a = *(const float4*)&w1p[h];
        float4 w1b = *(const float4*)&w1p[h + 4];
#define STEP(UU, VV, W0, W1)                                          \
        acc0 = fmaf(VV, fast_rcp(fast_exp2(UU + W0) + 1.0f), acc0);   \
        acc1 = fmaf(VV, fast_rcp(fast_exp2(UU + W1) + 1.0f), acc1);
        STEP(ua.x, va.x, w0a.x, w1a.x)
        STEP(ua.y, va.y, w0a.y, w1a.y)
        STEP(ua.z, va.z, w0a.z, w1a.z)
        STEP(ua.w, va.w, w0a.w, w1a.w)
        STEP(ub.x, vb.x, w0b.x, w1b.x)
        STEP(ub.y, vb.y, w0b.y, w1b.y)
        STEP(ub.z, vb.z, w0b.z, w1b.z)
        STEP(ub.w, vb.w, w0b.w, w1b.w)
#undef STEP
    }
    part[hh][0][j] = acc0;
    part[hh][1][j] = acc1;
    __syncthreads();

    // ---- combine halves + masks + probs (hh==0 waves, 2 rows each) ----
    if (hh == 0) {
        const float vsum = s_vsum;
        const bool colpad = (words[b * SS + j] == 0);
#pragma unroll
        for (int r = 0; r < 2; ++r) {
            const int i = i0 + r;
            float s = fmaf(-2.0f, part[0][r][j] + part[1][r][j], vsum);
            if (colpad || j == i) s = NEGV;
            s_sc[r][j] = s;
            if (i >= 1)
                out[1 + (size_t)(b * (SS - 1) + (i - 1)) * SS + j] = exp_fast(s);
        }
    }
    __syncthreads();

    // ---- softmax + CE (hh==1 waves: jh selects the row) ----
    if (hh == 1) {
        const int r = jh;
        const int i = i0 + r;
        float t0 = s_sc[r][lane];
        float t1 = s_sc[r][lane + 64];
        float m = fmaxf(t0, t1);
#pragma unroll
        for (int off = 32; off > 0; off >>= 1) m = fmaxf(m, __shfl_xor(m, off));
        float e = exp_fast(t0 - m) + exp_fast(t1 - m);
#pragma unroll
        for (int off = 32; off > 0; off >>= 1) e += __shfl_xor(e, off);

        const int hd = heads[b * SS + i];
        const float sh = s_sc[r][hd];
        const float ce = m + fast_log2(e) * LN2 - sh;
        if (lane == 0) ce_out[b * SS + i] = (i >= 1) ? ce : 0.f;
    }
}

// ------------------------------------------------------------------
// Kernel 3: deterministic loss reduction (f64 accumulate)
// ------------------------------------------------------------------
__global__ __launch_bounds__(256)
void loss_sum(const float* __restrict__ ce, float* __restrict__ out) {
    __shared__ double sd[256];
    const int tid = threadIdx.x;
    double s = 0.0;
    for (int k = tid; k < M_TOT; k += 256) s += (double)ce[k];
    sd[tid] = s;
    __syncthreads();
    for (int off = 128; off > 0; off >>= 1) {
        if (tid < off) sd[tid] += sd[tid + off];
        __syncthreads();
    }
    if (tid == 0) out[0] = (float)(sd[0] * (1.0 / (double)BB));
}

// ------------------------------------------------------------------
extern "C" void kernel_launch(void* const* d_in, const int* in_sizes, int n_in,
                              void* d_out, int out_size, void* d_ws, size_t ws_size,
                              hipStream_t stream) {
    const float* repr   = (const float*)d_in[0];   // [16,128,512]
    const float* labels = (const float*)d_in[1];   // [16,128,43]
    const int*   heads  = (const int*)d_in[2];     // [16,128]
    const int*   words  = (const int*)d_in[3];     // [16,128]
    // d_in[4] = sent_id (unused)
    const float* u_w    = (const float*)d_in[5];   // [555,512]
    const float* u_b    = (const float*)d_in[6];   // [512]
    const float* w_w    = (const float*)d_in[7];   // [555,512]
    const float* w_b    = (const float*)d_in[8];   // [512]
    const float* v_w    = (const float*)d_in[9];   // [512,1]

    float* out = (float*)d_out;                    // [0]=loss, rest probs [16,127,128]

    // ---- workspace layout (bytes) ----
    char* ws = (char*)d_ws;
    size_t cur = 0;
    float*  u_ws = (float*)(ws + cur);  cur += (size_t)M_TOT * HH * 4;        // 4 MB
    float*  w_ws = (float*)(ws + cur);  cur += (size_t)M_TOT * HH * 4;        // 4 MB
    bf16_t* Ah   = (bf16_t*)(ws + cur); cur += (size_t)M_TOT * KP * 2;        // 2.25 MB
    bf16_t* Al   = (bf16_t*)(ws + cur); cur += (size_t)M_TOT * KP * 2;
    bf16_t* Buh  = (bf16_t*)(ws + cur); cur += (size_t)HH * KP * 2;           // 0.56 MB
    bf16_t* Bul  = (bf16_t*)(ws + cur); cur += (size_t)HH * KP * 2;
    bf16_t* Bwh  = (bf16_t*)(ws + cur); cur += (size_t)HH * KP * 2;
    bf16_t* Bwl  = (bf16_t*)(ws + cur); cur += (size_t)HH * KP * 2;
    float*  ce_ws = (float*)(ws + cur);                                       // 8 KB

    split_kernel<<<dim3(1440), dim3(256), 0, stream>>>(
        repr, labels, u_w, w_w, Ah, Al, Buh, Bul, Bwh, Bwl);
    gemm_mfma<<<dim3(256), dim3(256), 0, stream>>>(
        Ah, Al, Buh, Bul, Bwh, Bwl, u_b, w_b, u_ws, w_ws);
    scores_v5<<<dim3(1024), dim3(256), 0, stream>>>(
        u_ws, w_ws, v_w, heads, words, out, ce_ws);
    loss_sum<<<dim3(1), dim3(256), 0, stream>>>(ce_ws, out);
}